// Round 2
// baseline (198.614 us; speedup 1.0000x reference)
//
#include <hip/hip_runtime.h>

// Problem constants (fixed by setup_inputs in the reference)
constexpr int N_  = 8;
constexpr int B_  = 64;
constexpr int C_  = 32;
constexpr int H_  = 256;
constexpr int W_  = 256;
constexpr int PH_ = 8;
constexpr int HW_ = H_ * W_;

__global__ __launch_bounds__(256)
void boxpool_kernel(const float* __restrict__ x, const float* __restrict__ boxes,
                    float* __restrict__ out, int MW, long featsSize)
{
    const int nb = blockIdx.x;          // 0..N*B-1, one block per box
    const int n  = nb >> 6;             // B_ = 64
    const int tid = threadIdx.x;

    // Box parameters — wave-uniform address -> scalar loads
    const float* bp = boxes + (long)nb * 4;
    const float xmin = bp[0], ymin = bp[1], xmax = bp[2], ymax = bp[3];
    const bool is_zero = (xmin == 0.f) && (ymin == 0.f) && (xmax == 0.f) && (ymax == 0.f);
    const float bw = xmax - xmin, bh = ymax - ymin;
    const bool wide = bw > bh;
    float den = wide ? bh : bw;
    den = (den == 0.f) ? 1.f : den;
    const float ratio = (wide ? bw : bh) / den;
    const float wf = ceilf(ratio * (float)PH_);
    const float wm1 = (wf > 1.f) ? (wf - 1.f) : 1.f;

    const float halfW = (float)W_ * 0.5f;
    const float halfH = (float)H_ * 0.5f;

    // widths tail: (N,B,2)
    if (tid < 2) out[featsSize + (long)nb * 2 + tid] = is_zero ? 0.f : wf;

    const int PM   = PH_ * MW;     // per-channel slice
    const int npts = 2 * PM;       // both directions
    const float* xb = x + (long)n * C_ * HW_;

    for (int p = tid; p < npts; p += 256) {
        int d = p / PM;
        int r = p - d * PM;
        int i = r / MW;
        int j = r - i * MW;

        // out index: (((nb*2+d)*C + c)*PH + i)*MW + j  -> base at c=0, stride PM
        float* op = out + (long)(nb * 2 + d) * C_ * PM + i * MW + j;

        const bool valid = !is_zero && ((float)j < wf);
        if (!valid) {
            #pragma unroll 8
            for (int c = 0; c < C_; ++c) op[(long)c * PM] = 0.f;
            continue;
        }

        float fi = (float)i, fj = (float)j;
        if (d == 1) { fi = (float)(PH_ - 1) - fi; fj = wf - 1.f - fj; }

        float gx, gy;
        if (wide) {
            float each_w = bw / wm1;
            float each_h = bh / (float)(PH_ - 1);
            gx = (xmin + fj * each_w - halfW) / halfW;
            gy = (ymin + fi * each_h - halfH) / halfH;
        } else {
            float each_w = bh / wm1;
            float each_h = bw / (float)(PH_ - 1);
            gx = (xmin + fi * each_h - halfW) / halfW;
            gy = ((wf - fj) * each_w + ymin - halfH) / halfH;
        }

        // grid_sample: bilinear, zeros padding, align_corners=False
        float ix = ((gx + 1.f) * (float)W_ - 1.f) * 0.5f;
        float iy = ((gy + 1.f) * (float)H_ - 1.f) * 0.5f;
        float x0f = floorf(ix);
        float y0f = floorf(iy);

        float wx1 = ix - x0f, wx0 = 1.f - wx1;   // weights for x0, x0+1
        float wy1 = iy - y0f, wy0 = 1.f - wy1;

        // fold per-corner validity into weights; gather from clamped indices
        bool vx0 = (x0f >= 0.f) && (x0f < (float)W_);
        bool vx1 = (x0f + 1.f >= 0.f) && (x0f + 1.f < (float)W_);
        bool vy0 = (y0f >= 0.f) && (y0f < (float)H_);
        bool vy1 = (y0f + 1.f >= 0.f) && (y0f + 1.f < (float)H_);
        if (!vx0) wx0 = 0.f;
        if (!vx1) wx1 = 0.f;
        if (!vy0) wy0 = 0.f;
        if (!vy1) wy1 = 0.f;

        int x0c = (int)fminf(fmaxf(x0f,       0.f), (float)(W_ - 1));
        int x1c = (int)fminf(fmaxf(x0f + 1.f, 0.f), (float)(W_ - 1));
        int y0c = (int)fminf(fmaxf(y0f,       0.f), (float)(H_ - 1));
        int y1c = (int)fminf(fmaxf(y0f + 1.f, 0.f), (float)(H_ - 1));

        int o00 = y0c * W_ + x0c;
        int o01 = y0c * W_ + x1c;
        int o10 = y1c * W_ + x0c;
        int o11 = y1c * W_ + x1c;

        float w00 = wx0 * wy0, w01 = wx1 * wy0;
        float w10 = wx0 * wy1, w11 = wx1 * wy1;

        #pragma unroll 8
        for (int c = 0; c < C_; ++c) {
            const float* xc = xb + (long)c * HW_;
            float acc = w00 * xc[o00] + w01 * xc[o01]
                      + w10 * xc[o10] + w11 * xc[o11];
            op[(long)c * PM] = acc;
        }
    }
}

extern "C" void kernel_launch(void* const* d_in, const int* in_sizes, int n_in,
                              void* d_out, int out_size, void* d_ws, size_t ws_size,
                              hipStream_t stream)
{
    const float* x     = (const float*)d_in[0];
    const float* boxes = (const float*)d_in[1];
    float* out = (float*)d_out;

    long total      = (long)out_size;
    long widthsSize = (long)N_ * B_ * 2;
    long featsSize  = total - widthsSize;
    int  MW         = (int)(featsSize / ((long)N_ * B_ * 2 * C_ * PH_));

    hipLaunchKernelGGL(boxpool_kernel, dim3(N_ * B_), dim3(256), 0, stream,
                       x, boxes, out, MW, featsSize);
}